// Round 1
// baseline (506.489 us; speedup 1.0000x reference)
//
#include <hip/hip_runtime.h>

typedef __attribute__((ext_vector_type(8))) _Float16 half8;
typedef __attribute__((ext_vector_type(4))) float f32x4;

#define N1_ 100000
#define N2_ 200000
#define N3_ 300000
#define N4_ 400000

typedef __attribute__((address_space(1))) const void gconst_t;
typedef __attribute__((address_space(3))) void lds_t;

__device__ __forceinline__ unsigned short f2h_bits(float x) {
  union { _Float16 h; unsigned short u; } cv;
  cv.h = (_Float16)x;
  return cv.u;
}

__device__ __forceinline__ f32x4 mfma16(half8 a, half8 b, f32x4 c) {
  return __builtin_amdgcn_mfma_f32_16x16x32_f16(a, b, c, 0, 0, 0);
}

// ---- convert h (fp32) -> fp16 bits --------------------------------------
__global__ void cvt_h_kernel(const float* __restrict__ h,
                             unsigned short* __restrict__ hf, int n4) {
  int i = blockIdx.x * blockDim.x + threadIdx.x;
  if (i >= n4) return;
  float4 v = reinterpret_cast<const float4*>(h)[i];
  ushort4 o;
  o.x = f2h_bits(v.x); o.y = f2h_bits(v.y);
  o.z = f2h_bits(v.z); o.w = f2h_bits(v.w);
  reinterpret_cast<ushort4*>(hf)[i] = o;
}

// ---- pack weights into MFMA B-fragment order ----------------------------
// packed[kt*4096 + nt*512 + lane*8 + j] = W[kt*32 + (lane>>4)*8 + j][nt*16 + (lane&15)]
struct PackInfo {
  const float* W[12];
  int kt_base[13];
  int out_off[12];
};

__global__ void pack_w_kernel(PackInfo info, unsigned short* __restrict__ pw) {
  int b = blockIdx.x;
  int lane = threadIdx.x;  // 64 threads
  int m = 0;
  while (m < 11 && b >= info.kt_base[m + 1]) ++m;
  int kt = b - info.kt_base[m];
  const float* W = info.W[m];
  int lr = lane & 15, kb = lane >> 4;
  unsigned short* outp = pw + info.out_off[m] + (size_t)kt * 4096 + lane * 8;
  #pragma unroll
  for (int nt = 0; nt < 8; ++nt) {
    #pragma unroll
    for (int j = 0; j < 8; ++j) {
      int krow = kt * 32 + kb * 8 + j;
      int col = nt * 16 + lr;
      outp[nt * 512 + j] = f2h_bits(W[(size_t)krow * 128 + col]);
    }
  }
}

// ---- main level kernel --------------------------------------------------
// One wave = one 16-row tile. 4 waves/block. B-slabs staged in LDS
// (double-buffered, global_load_lds), shared across waves; backward
// direction reuses the same slab with mirrored A-segment.
template <int K, int NHEAD>
__global__ __launch_bounds__(256, 3) void level_kernel(
    const unsigned short* __restrict__ hf,
    const int* __restrict__ idx,
    const unsigned short* __restrict__ pw,  // packed W0|W1|W2 (fp16 bits)
    const float* __restrict__ b0, const float* __restrict__ b1,
    const float* __restrict__ b2,
    const float* __restrict__ hw0, const float* __restrict__ hb0,
    float* __restrict__ out0,
    const float* __restrict__ hw1, const float* __restrict__ hb1,
    float* __restrict__ out1,
    const float* __restrict__ hw2, const float* __restrict__ hb2,
    float* __restrict__ out2,
    int N) {
  constexpr int NDIR = (K > 1) ? 2 : 1;
  constexpr int KT0 = 4 * K;

  __shared__ __align__(16) unsigned short bstage[2][4096];        // 16 KB
  __shared__ __align__(16) unsigned short act[4][NDIR][2048];     // 16/32 KB

  const int lane = threadIdx.x & 63;
  const int wid = threadIdx.x >> 6;
  const int lrow = lane & 15;
  const int kb = lane >> 4;

  int tile = blockIdx.x * 4 + wid;
  const int maxtile = N / 16 - 1;
  const bool writer = (tile <= maxtile);
  if (!writer) tile = maxtile;  // clamp: all waves run (barriers!), only writer stores
  const int row = tile * 16 + lrow;

  int src[K];
  #pragma unroll
  for (int s = 0; s < K; ++s) src[s] = (K == 1) ? row : idx[(size_t)row * K + s];

  // -- staging: 8 KB slab, 2 x 1KB per wave via global_load_lds width 16
  auto stage = [&](int buf, const unsigned short* slab) {
    #pragma unroll
    for (int c = 0; c < 2; ++c) {
      const unsigned short* g = slab + (wid * 2 + c) * 512 + lane * 8;
      unsigned short* l = &bstage[buf][(wid * 2 + c) * 512];
      __builtin_amdgcn_global_load_lds((gconst_t*)g, (lds_t*)l, 16, 0, 0);
    }
  };

  int cur = 0;
  // generic staged layer: accumulates into accF (and accB when NDIR==2),
  // one barrier per K-slab, double-buffered prefetch.
  auto run_layer = [&](const unsigned short* w, int nkt, auto&& getAf,
                       auto&& getAb, f32x4* accF, f32x4* accB) {
    stage(cur, w);
    __syncthreads();
    for (int kt = 0; kt < nkt; ++kt) {
      if (kt + 1 < nkt) stage(cur ^ 1, w + (size_t)(kt + 1) * 4096);
      half8 af = getAf(kt);
      half8 ab;
      if constexpr (NDIR == 2) ab = getAb(kt);
      #pragma unroll
      for (int nt = 0; nt < 8; ++nt) {
        half8 bq = *reinterpret_cast<const half8*>(&bstage[cur][nt * 512 + lane * 8]);
        accF[nt] = mfma16(af, bq, accF[nt]);
        if constexpr (NDIR == 2) accB[nt] = mfma16(ab, bq, accB[nt]);
      }
      __syncthreads();
      cur ^= 1;
    }
  };

  // layer-0 A fragments straight from gathered h rows (fp16, 16B/lane)
  auto A0f = [&](int kt) {
    int seg = kt >> 2, sub = kt & 3;
    return *reinterpret_cast<const half8*>(hf + (size_t)src[seg] * 128 + sub * 32 + kb * 8);
  };
  auto A0b = [&](int kt) {
    int seg = K - 1 - (kt >> 2), sub = kt & 3;
    return *reinterpret_cast<const half8*>(hf + (size_t)src[seg] * 128 + sub * 32 + kb * 8);
  };
  // layers 1/2: A from per-wave activation LDS (XOR-swizzled rows)
  auto actRead = [&](int dir, int kt) -> half8 {
    unsigned off = (unsigned)(lrow * 256 + (kt * 32 + kb * 8) * 2) ^ ((unsigned)(lrow & 7) << 4);
    return *reinterpret_cast<const half8*>(
        reinterpret_cast<const unsigned char*>(&act[wid][dir][0]) + off);
  };
  auto actA0 = [&](int kt) { return actRead(0, kt); };
  auto actA1 = [&](int kt) { return actRead(NDIR == 2 ? 1 : 0, kt); };

  // bias + relu + fp16 store to swizzled act LDS (D-frag: row=4*kb+r, col=nt*16+lrow)
  auto store_act = [&](const f32x4* acc, const float* bias, int dir) {
    unsigned char* base = reinterpret_cast<unsigned char*>(&act[wid][dir][0]);
    #pragma unroll
    for (int nt = 0; nt < 8; ++nt) {
      float bv = bias[nt * 16 + lrow];
      #pragma unroll
      for (int r = 0; r < 4; ++r) {
        float v = fmaxf(acc[nt][r] + bv, 0.f);
        int trow = 4 * kb + r;
        unsigned off = (unsigned)(trow * 256 + (nt * 16 + lrow) * 2) ^ ((unsigned)(trow & 7) << 4);
        *reinterpret_cast<unsigned short*>(base + off) = f2h_bits(v);
      }
    }
  };

  f32x4 aF[8], aB[8];
  auto zero_acc = [&](f32x4* a) {
    #pragma unroll
    for (int nt = 0; nt < 8; ++nt) a[nt] = f32x4{0.f, 0.f, 0.f, 0.f};
  };

  // ---- layer 0 ----
  zero_acc(aF); zero_acc(aB);
  run_layer(pw, KT0, A0f, A0b, aF, aB);
  store_act(aF, b0, 0);
  if constexpr (NDIR == 2) store_act(aB, b0, 1);

  // ---- layer 1 ----
  zero_acc(aF); zero_acc(aB);
  run_layer(pw + (size_t)KT0 * 4096, 4, actA0, actA1, aF, aB);
  store_act(aF, b1, 0);
  if constexpr (NDIR == 2) store_act(aB, b1, 1);

  // ---- layer 2 ----
  zero_acc(aF); zero_acc(aB);
  run_layer(pw + (size_t)KT0 * 4096 + 16384, 4, actA0, actA1, aF, aB);

  f32x4 y[8];
  #pragma unroll
  for (int nt = 0; nt < 8; ++nt) {
    float bv = b2[nt * 16 + lrow];
    #pragma unroll
    for (int r = 0; r < 4; ++r) {
      float v = fmaxf(aF[nt][r] + bv, 0.f);
      if constexpr (NDIR == 2) v += fmaxf(aB[nt][r] + bv, 0.f);
      y[nt][r] = v;
    }
  }

  // ---- heads: fp32 dot + 16-lane shuffle reduce ----
  const float* hws[3] = {hw0, hw1, hw2};
  const float* hbs[3] = {hb0, hb1, hb2};
  float* outs[3] = {out0, out1, out2};
  #pragma unroll
  for (int hd = 0; hd < NHEAD; ++hd) {
    float p[4] = {0.f, 0.f, 0.f, 0.f};
    #pragma unroll
    for (int nt = 0; nt < 8; ++nt) {
      float w = hws[hd][nt * 16 + lrow];
      #pragma unroll
      for (int r = 0; r < 4; ++r) p[r] += y[nt][r] * w;
    }
    #pragma unroll
    for (int m = 1; m < 16; m <<= 1) {
      #pragma unroll
      for (int r = 0; r < 4; ++r) p[r] += __shfl_xor(p[r], m, 64);
    }
    if (writer && lrow < 4) {
      float pv = (lrow == 0) ? p[0] : (lrow == 1) ? p[1] : (lrow == 2) ? p[2] : p[3];
      outs[hd][tile * 16 + 4 * kb + lrow] = pv + hbs[hd][0];
    }
  }
}

// -------------------------------------------------------------------------
extern "C" void kernel_launch(void* const* d_in, const int* in_sizes, int n_in,
                              void* d_out, int out_size, void* d_ws, size_t ws_size,
                              hipStream_t stream) {
  (void)in_sizes; (void)n_in; (void)out_size;

  const float* h = (const float*)d_in[0];
  const int* idx2 = (const int*)d_in[1];
  const int* idx3 = (const int*)d_in[2];
  const int* idx4 = (const int*)d_in[3];

  const float* sW[4][3];
  const float* sb[4][3];
  for (int L = 0; L < 4; ++L)
    for (int j = 0; j < 3; ++j) {
      sW[L][j] = (const float*)d_in[4 + L * 6 + j * 2];
      sb[L][j] = (const float*)d_in[4 + L * 6 + j * 2 + 1];
    }
  // heads: h1_sigma, h1_epsilon, h1_q, h2_k, h2_eq, h3_k, h3_eq, h4_k, h4_eq
  const float* hW[9];
  const float* hB[9];
  for (int i = 0; i < 9; ++i) {
    hW[i] = (const float*)d_in[28 + i * 2];
    hB[i] = (const float*)d_in[28 + i * 2 + 1];
  }

  // workspace: fp16 h (12.8M elems) + packed weights (294912 elems)
  size_t need = ((size_t)N1_ * 128 + 294912) * 2;
  if (ws_size < need) return;
  unsigned short* hf = (unsigned short*)d_ws;
  unsigned short* pw = hf + (size_t)N1_ * 128;

  cvt_h_kernel<<<(N1_ * 128 / 4 + 255) / 256, 256, 0, stream>>>(h, hf, N1_ * 128 / 4);

  PackInfo pi;
  const int din[12] = {128, 128, 128, 256, 128, 128, 384, 128, 128, 512, 128, 128};
  int ktb = 0, ooff = 0;
  for (int m = 0; m < 12; ++m) {
    pi.W[m] = sW[m / 3][m % 3];
    pi.kt_base[m] = ktb;
    pi.out_off[m] = ooff;
    ktb += din[m] / 32;
    ooff += din[m] * 128;
  }
  pi.kt_base[12] = ktb;  // 72
  pack_w_kernel<<<ktb, 64, 0, stream>>>(pi, pw);

  float* out = (float*)d_out;
  float* o_sigma = out;
  float* o_eps = out + N1_;
  float* o_q = out + 2 * N1_;
  float* o_k2 = out + 3 * N1_;
  float* o_eq2 = o_k2 + N2_;
  float* o_k3 = o_eq2 + N2_;
  float* o_eq3 = o_k3 + N3_;
  float* o_k4 = o_eq3 + N3_;
  float* o_eq4 = o_k4 + N4_;

  level_kernel<1, 3><<<(N1_ / 16 + 3) / 4, 256, 0, stream>>>(
      hf, nullptr, pw + pi.out_off[0], sb[0][0], sb[0][1], sb[0][2],
      hW[0], hB[0], o_sigma, hW[1], hB[1], o_eps, hW[2], hB[2], o_q, N1_);
  level_kernel<2, 2><<<(N2_ / 16 + 3) / 4, 256, 0, stream>>>(
      hf, idx2, pw + pi.out_off[3], sb[1][0], sb[1][1], sb[1][2],
      hW[3], hB[3], o_k2, hW[4], hB[4], o_eq2, nullptr, nullptr, nullptr, N2_);
  level_kernel<3, 2><<<(N3_ / 16 + 3) / 4, 256, 0, stream>>>(
      hf, idx3, pw + pi.out_off[6], sb[2][0], sb[2][1], sb[2][2],
      hW[5], hB[5], o_k3, hW[6], hB[6], o_eq3, nullptr, nullptr, nullptr, N3_);
  level_kernel<4, 2><<<(N4_ / 16 + 3) / 4, 256, 0, stream>>>(
      hf, idx4, pw + pi.out_off[9], sb[3][0], sb[3][1], sb[3][2],
      hW[7], hB[7], o_k4, hW[8], hB[8], o_eq4, nullptr, nullptr, nullptr, N4_);
}